// Round 1
// baseline (748.318 us; speedup 1.0000x reference)
//
#include <hip/hip_runtime.h>

typedef unsigned short u16;
typedef unsigned int   u32;

#define CIN  20
#define DIN  32
#define NST  8
#define RNK  4
#define BB   4
#define HH   384
#define WW   384
#define HW   147456
#define BHW  589824
#define NSEQ 1536
#define EPSF 1e-5f

__device__ __forceinline__ float bf2f(u16 h) {
    union { u32 u; float f; } v; v.u = ((u32)h) << 16; return v.f;
}
__device__ __forceinline__ u16 f2bf(float f) {
    union { float f; u32 u; } v; v.f = f;
    u32 u = v.u;
    return (u16)((u + 0x7FFFu + ((u >> 16) & 1u)) >> 16);
}
__device__ __forceinline__ float silu_f(float a) {
    return a / (1.f + __expf(-a));
}

// ---------------- K0: fold merge+out weights ----------------
// Wt[k][o] = merge_g[k] * sum_d out_w[o][d]*merge_w[d][k]   (128 x 20)
// rsum[o]  = sum_k Wt[k][o]
// c0[o]    = out_b[o] + sum_d out_w[o][d] * (sum_k merge_w[d][k]*merge_b[k])
__global__ void k_prep(const float* __restrict__ ow, const float* __restrict__ mw,
                       const float* __restrict__ mg, const float* __restrict__ mb,
                       const float* __restrict__ ob,
                       float* __restrict__ Wt, float* __restrict__ rsum,
                       float* __restrict__ c0)
{
    __shared__ float mdot[DIN];
    int t = threadIdx.x; // 128 threads
    if (t < DIN) {
        float s = 0.f;
        for (int k = 0; k < 128; ++k) s += mw[t*128 + k] * mb[k];
        mdot[t] = s;
    }
    {
        int k = t;
        for (int o = 0; o < CIN; ++o) {
            float s = 0.f;
            for (int d = 0; d < DIN; ++d) s += ow[o*DIN + d] * mw[d*128 + k];
            Wt[k*CIN + o] = s * mg[k];
        }
    }
    __syncthreads();
    if (t < CIN) {
        float rs = 0.f;
        for (int k = 0; k < 128; ++k) rs += Wt[k*CIN + t];
        rsum[t] = rs;
        float c = ob[t];
        for (int d = 0; d < DIN; ++d) c += ow[t*DIN + d] * mdot[d];
        c0[t] = c;
    }
}

// ---------------- K1: layernorm(C=20) + inproj(20->32) + silu ----------------
__global__ __launch_bounds__(256) void k_lnproj(
    const float* __restrict__ x, const float* __restrict__ ng,
    const float* __restrict__ nb, const float* __restrict__ ipw, // 32x20
    u16* __restrict__ h1)
{
    __shared__ float w_s[DIN*CIN];
    __shared__ float g_s[CIN], b_s[CIN];
    for (int i = threadIdx.x; i < DIN*CIN; i += 256) w_s[i] = ipw[i];
    if (threadIdx.x < CIN) { g_s[threadIdx.x] = ng[threadIdx.x]; b_s[threadIdx.x] = nb[threadIdx.x]; }
    __syncthreads();

    int p = blockIdx.x*256 + threadIdx.x;
    int b = p / HW, rem = p % HW;
    float v[CIN];
    float m = 0.f;
    #pragma unroll
    for (int c = 0; c < CIN; ++c) { v[c] = x[(b*CIN + c)*HW + rem]; m += v[c]; }
    m *= (1.f/CIN);
    float var = 0.f;
    #pragma unroll
    for (int c = 0; c < CIN; ++c) { float d = v[c]-m; var += d*d; }
    var *= (1.f/CIN);
    float rstd = rsqrtf(var + EPSF);
    #pragma unroll
    for (int c = 0; c < CIN; ++c) v[c] = (v[c]-m)*rstd*g_s[c] + b_s[c];

    float o[DIN];
    #pragma unroll
    for (int j = 0; j < DIN; ++j) {
        float acc = 0.f;
        #pragma unroll
        for (int c = 0; c < CIN; ++c) acc += w_s[j*CIN + c]*v[c];
        o[j] = silu_f(acc);
    }
    u32 pk[16];
    #pragma unroll
    for (int j2 = 0; j2 < 16; ++j2)
        pk[j2] = (u32)f2bf(o[2*j2]) | ((u32)f2bf(o[2*j2+1]) << 16);
    uint4* dst = (uint4*)(h1 + (size_t)p*DIN);
    dst[0] = make_uint4(pk[0],pk[1],pk[2],pk[3]);
    dst[1] = make_uint4(pk[4],pk[5],pk[6],pk[7]);
    dst[2] = make_uint4(pk[8],pk[9],pk[10],pk[11]);
    dst[3] = make_uint4(pk[12],pk[13],pk[14],pk[15]);
}

// ---------------- K2: depthwise 3x3 conv + bias + silu ----------------
__global__ __launch_bounds__(256) void k_conv(
    const u16* __restrict__ h1, const float* __restrict__ cw, // (3,3,1,32)
    const float* __restrict__ cb, u16* __restrict__ h2)
{
    __shared__ float w_s[9*DIN];
    __shared__ float b_s[DIN];
    for (int i = threadIdx.x; i < 9*DIN; i += 256) w_s[i] = cw[i];
    if (threadIdx.x < DIN) b_s[threadIdx.x] = cb[threadIdx.x];
    __syncthreads();

    int tid = blockIdx.x*256 + threadIdx.x;
    int p = tid >> 2, g = tid & 3;          // 8 channels per thread
    int b = p / HW, rem = p % HW;
    int yy0 = rem / WW, xx0 = rem % WW;

    float acc[8];
    #pragma unroll
    for (int i = 0; i < 8; ++i) acc[i] = b_s[g*8 + i];

    #pragma unroll
    for (int dy = -1; dy <= 1; ++dy) {
        int yy = yy0 + dy;
        #pragma unroll
        for (int dx = -1; dx <= 1; ++dx) {
            int xc = xx0 + dx;
            if (yy >= 0 && yy < HH && xc >= 0 && xc < WW) {
                uint4 q = *(const uint4*)(h1 + ((size_t)(b*HW + yy*WW + xc)*DIN + g*8));
                int k = (dy+1)*3 + (dx+1);
                const float* wp = &w_s[k*DIN + g*8];
                acc[0] += wp[0]*bf2f((u16)q.x);  acc[1] += wp[1]*bf2f((u16)(q.x>>16));
                acc[2] += wp[2]*bf2f((u16)q.y);  acc[3] += wp[3]*bf2f((u16)(q.y>>16));
                acc[4] += wp[4]*bf2f((u16)q.z);  acc[5] += wp[5]*bf2f((u16)(q.z>>16));
                acc[6] += wp[6]*bf2f((u16)q.w);  acc[7] += wp[7]*bf2f((u16)(q.w>>16));
            }
        }
    }
    u32 pk[4];
    #pragma unroll
    for (int i2 = 0; i2 < 4; ++i2) {
        float a = silu_f(acc[2*i2]);
        float c = silu_f(acc[2*i2+1]);
        pk[i2] = (u32)f2bf(a) | ((u32)f2bf(c) << 16);
    }
    *(uint4*)(h2 + ((size_t)p*DIN + g*8)) = make_uint4(pk[0],pk[1],pk[2],pk[3]);
}

// ---------------- K3: xdbl = u @ xw^T per direction (20 outs) ----------------
__global__ __launch_bounds__(256) void k_proj(
    const u16* __restrict__ h2, const float* __restrict__ xw, // (4,20,32)
    u16* __restrict__ proj)
{
    __shared__ float xw_s[4*CIN*DIN]; // 10 KB
    for (int i = threadIdx.x; i < 4*CIN*DIN; i += 256) xw_s[i] = xw[i];
    __syncthreads();

    int p = blockIdx.x*256 + threadIdx.x;
    float u[DIN];
    const uint4* src = (const uint4*)(h2 + (size_t)p*DIN);
    #pragma unroll
    for (int q4 = 0; q4 < 4; ++q4) {
        uint4 v = src[q4];
        u[q4*8+0]=bf2f((u16)v.x); u[q4*8+1]=bf2f((u16)(v.x>>16));
        u[q4*8+2]=bf2f((u16)v.y); u[q4*8+3]=bf2f((u16)(v.y>>16));
        u[q4*8+4]=bf2f((u16)v.z); u[q4*8+5]=bf2f((u16)(v.z>>16));
        u[q4*8+6]=bf2f((u16)v.w); u[q4*8+7]=bf2f((u16)(v.w>>16));
    }
    #pragma unroll 1
    for (int dir = 0; dir < 4; ++dir) {
        float xd[CIN];
        #pragma unroll
        for (int j = 0; j < CIN; ++j) xd[j] = 0.f;
        #pragma unroll
        for (int d4 = 0; d4 < 8; ++d4) {
            float u0 = u[d4*4], u1 = u[d4*4+1], u2 = u[d4*4+2], u3 = u[d4*4+3];
            #pragma unroll
            for (int j = 0; j < CIN; ++j) {
                float4 w4 = *(const float4*)&xw_s[(dir*CIN + j)*DIN + d4*4];
                xd[j] += w4.x*u0 + w4.y*u1 + w4.z*u2 + w4.w*u3;
            }
        }
        u32 pk[10];
        #pragma unroll
        for (int i = 0; i < 10; ++i)
            pk[i] = (u32)f2bf(xd[2*i]) | ((u32)f2bf(xd[2*i+1]) << 16);
        uint2* dst = (uint2*)(proj + ((size_t)dir*BHW + p)*CIN);
        dst[0] = make_uint2(pk[0],pk[1]);
        dst[1] = make_uint2(pk[2],pk[3]);
        dst[2] = make_uint2(pk[4],pk[5]);
        dst[3] = make_uint2(pk[6],pk[7]);
        dst[4] = make_uint2(pk[8],pk[9]);
    }
}

// ---------------- K4: 4-direction selective scan ----------------
// 1 wave per sequence; lane = d*2+g; lane holds states n = 4g..4g+3.
__global__ __launch_bounds__(256) void k_scan(
    const u16* __restrict__ h2, const u16* __restrict__ proj,
    const float* __restrict__ Alog, // (4,32,8)
    const float* __restrict__ Dp,   // (4,32)
    const float* __restrict__ dwm,  // (4,32,4)
    const float* __restrict__ dbv,  // (4,32)
    u16* __restrict__ y4)
{
    int wid  = blockIdx.x*4 + (threadIdx.x >> 6);
    int lane = threadIdx.x & 63;
    int dir  = wid / NSEQ;
    int s    = wid % NSEQ;
    int d    = lane >> 1, g = lane & 1;
    int b    = s / 384, r = s % 384;

    int p0, stp;
    if (dir == 0)      { p0 = b*HW + r*WW;           stp = 1;  }
    else if (dir == 1) { p0 = b*HW + r*WW + (WW-1);  stp = -1; }
    else if (dir == 2) { p0 = b*HW + r;              stp = WW; }
    else               { p0 = b*HW + (HH-1)*WW + r;  stp = -WW;}

    float A[4], dwr[4];
    #pragma unroll
    for (int j = 0; j < 4; ++j) {
        A[j]   = -__expf(Alog[(dir*DIN + d)*NST + g*4 + j]);
        dwr[j] = dwm[(dir*DIN + d)*RNK + j];
    }
    float db = dbv[dir*DIN + d];
    float Dd = Dp[dir*DIN + d];

    const u16* qb = proj + (size_t)dir*BHW*CIN;
    float h0 = 0.f, h1v = 0.f, h2v = 0.f, h3v = 0.f;

    int off = p0;
    u16   u_r  = h2[off*DIN + d];
    uint2 dl_r = *(const uint2*)(qb + off*CIN);
    uint2 B_r  = *(const uint2*)(qb + off*CIN + 4 + 4*g);
    uint2 C_r  = *(const uint2*)(qb + off*CIN + 12 + 4*g);

    for (int t = 0; t < 384; ++t) {
        float uu  = bf2f(u_r);
        float dl0 = bf2f((u16)dl_r.x), dl1 = bf2f((u16)(dl_r.x>>16));
        float dl2 = bf2f((u16)dl_r.y), dl3 = bf2f((u16)(dl_r.y>>16));
        float B0 = bf2f((u16)B_r.x), B1 = bf2f((u16)(B_r.x>>16));
        float B2 = bf2f((u16)B_r.y), B3 = bf2f((u16)(B_r.y>>16));
        float C0 = bf2f((u16)C_r.x), C1 = bf2f((u16)(C_r.x>>16));
        float C2 = bf2f((u16)C_r.y), C3 = bf2f((u16)(C_r.y>>16));

        int noff = (t < 383) ? off + stp : off;
        u_r  = h2[noff*DIN + d];
        dl_r = *(const uint2*)(qb + noff*CIN);
        B_r  = *(const uint2*)(qb + noff*CIN + 4 + 4*g);
        C_r  = *(const uint2*)(qb + noff*CIN + 12 + 4*g);

        float z = db + dwr[0]*dl0 + dwr[1]*dl1 + dwr[2]*dl2 + dwr[3]*dl3;
        float e = __expf(z);
        float dt = (z > 15.f) ? z : __logf(1.f + e);
        float dtu = dt*uu;

        float a0 = __expf(dt*A[0]); h0 = a0*h0 + dtu*B0;
        float a1 = __expf(dt*A[1]); h1v = a1*h1v + dtu*B1;
        float a2 = __expf(dt*A[2]); h2v = a2*h2v + dtu*B2;
        float a3 = __expf(dt*A[3]); h3v = a3*h3v + dtu*B3;
        float yacc = C0*h0 + C1*h1v + C2*h2v + C3*h3v;

        float yo = __shfl_xor(yacc, 1, 64);
        float yd = yacc + yo + Dd*uu;
        if (g == 0) y4[(size_t)off*128 + dir*DIN + d] = f2bf(yd);
        off = noff;
    }
}

// ---------------- K5: LN(128) + folded 128->20 + NCHW transpose ----------------
__global__ __launch_bounds__(256) void k_merge(
    const u16* __restrict__ y4, const float* __restrict__ Wt,
    const float* __restrict__ rsum, const float* __restrict__ c0,
    float* __restrict__ out)
{
    __shared__ float Wt_s[128*CIN]; // 10 KB
    __shared__ float rs_s[CIN], c0_s[CIN];
    for (int i = threadIdx.x; i < 128*CIN; i += 256) Wt_s[i] = Wt[i];
    if (threadIdx.x < CIN) { rs_s[threadIdx.x] = rsum[threadIdx.x]; c0_s[threadIdx.x] = c0[threadIdx.x]; }
    __syncthreads();

    int p = blockIdx.x*256 + threadIdx.x;
    int b = p / HW, rem = p % HW;
    const uint4* src = (const uint4*)(y4 + (size_t)p*128);

    float s1 = 0.f, s2 = 0.f;
    #pragma unroll 4
    for (int q4 = 0; q4 < 16; ++q4) {
        uint4 v = src[q4];
        u32 w[4] = {v.x, v.y, v.z, v.w};
        #pragma unroll
        for (int i = 0; i < 4; ++i) {
            float a = bf2f((u16)w[i]); float c = bf2f((u16)(w[i]>>16));
            s1 += a + c; s2 += a*a + c*c;
        }
    }
    float m = s1*(1.f/128.f);
    float var = s2*(1.f/128.f) - m*m;
    float rstd = rsqrtf(var + EPSF);

    float acc[CIN];
    #pragma unroll
    for (int o = 0; o < CIN; ++o) acc[o] = 0.f;

    #pragma unroll 2
    for (int q4 = 0; q4 < 16; ++q4) {
        uint4 v = src[q4];
        u32 w[4] = {v.x, v.y, v.z, v.w};
        #pragma unroll
        for (int i = 0; i < 4; ++i) {
            int k = q4*8 + i*2;
            float a = bf2f((u16)w[i]); float c = bf2f((u16)(w[i]>>16));
            const float4* w0 = (const float4*)&Wt_s[k*CIN];
            const float4* w1 = (const float4*)&Wt_s[(k+1)*CIN];
            #pragma unroll
            for (int o4 = 0; o4 < 5; ++o4) {
                float4 x0 = w0[o4], x1 = w1[o4];
                acc[o4*4+0] += x0.x*a + x1.x*c;
                acc[o4*4+1] += x0.y*a + x1.y*c;
                acc[o4*4+2] += x0.z*a + x1.z*c;
                acc[o4*4+3] += x0.w*a + x1.w*c;
            }
        }
    }
    #pragma unroll
    for (int o = 0; o < CIN; ++o) {
        float res = rstd*(acc[o] - m*rs_s[o]) + c0_s[o];
        out[(b*CIN + o)*HW + rem] = res;
    }
}

extern "C" void kernel_launch(void* const* d_in, const int* in_sizes, int n_in,
                              void* d_out, int out_size, void* d_ws, size_t ws_size,
                              hipStream_t stream)
{
    const float* x    = (const float*)d_in[0];
    const float* ng   = (const float*)d_in[1];
    const float* nb   = (const float*)d_in[2];
    const float* ipw  = (const float*)d_in[3];
    const float* cw   = (const float*)d_in[4];
    const float* cb   = (const float*)d_in[5];
    const float* xw   = (const float*)d_in[6];
    const float* dwm  = (const float*)d_in[7];
    const float* dbv  = (const float*)d_in[8];
    const float* Alog = (const float*)d_in[9];
    const float* Dpv  = (const float*)d_in[10];
    const float* mg   = (const float*)d_in[11];
    const float* mb   = (const float*)d_in[12];
    const float* mw   = (const float*)d_in[13];
    const float* ow   = (const float*)d_in[14];
    const float* ob   = (const float*)d_in[15];
    float* out = (float*)d_out;

    const size_t y4_bytes   = (size_t)BHW*128*2;        // 150,994,944
    const size_t proj_bytes = (size_t)4*BHW*CIN*2;      //  94,371,840
    char* ws = (char*)d_ws;
    u16*  y4   = (u16*)ws;
    u16*  h1   = y4;                                    // alias: dead before y4 written
    u16*  proj = (u16*)(ws + y4_bytes);
    float* Wt   = (float*)(ws + y4_bytes + proj_bytes);
    float* rsum = Wt + 128*CIN;
    float* c0   = rsum + 32;
    size_t need = y4_bytes + proj_bytes + (128*CIN + 64)*4;

    u16* h2 = (u16*)d_out;  // 37.7 MB scratch inside 47.2 MB output; overwritten by k_merge

    if (ws_size < need) {
        // sentinel: makes a ws-size failure diagnosable from absmax (~3.39e38)
        hipMemsetAsync(d_out, 0x7F, (size_t)out_size*4, stream);
        return;
    }

    k_prep  <<<1, 128, 0, stream>>>(ow, mw, mg, mb, ob, Wt, rsum, c0);
    k_lnproj<<<BHW/256, 256, 0, stream>>>(x, ng, nb, ipw, h1);
    k_conv  <<<BHW*4/256, 256, 0, stream>>>(h1, cw, cb, h2);
    k_proj  <<<BHW/256, 256, 0, stream>>>(h2, xw, proj);
    k_scan  <<<NSEQ*4/4, 256, 0, stream>>>(h2, proj, Alog, Dpv, dwm, dbv, y4);
    k_merge <<<BHW/256, 256, 0, stream>>>(y4, Wt, rsum, c0, out);
}

// Round 2
// 658.681 us; speedup vs baseline: 1.1361x; 1.1361x over previous
//
#include <hip/hip_runtime.h>

typedef unsigned short u16;
typedef unsigned int   u32;
typedef float f2 __attribute__((ext_vector_type(2)));

#define CIN  20
#define DIN  32
#define BB   4
#define HH   384
#define WW   384
#define HW   147456
#define BHW  589824
#define EPSF 1e-5f
#define GUARD 65536

__device__ __forceinline__ float bflo(u32 u) {
    union { u32 v; float f; } x; x.v = u << 16; return x.f;
}
__device__ __forceinline__ float bfhi(u32 u) {
    union { u32 v; float f; } x; x.v = u & 0xffff0000u; return x.f;
}
__device__ __forceinline__ float bf2f(u16 h) {
    union { u32 v; float f; } x; x.v = ((u32)h) << 16; return x.f;
}
__device__ __forceinline__ u16 f2bf(float f) {
    union { float f; u32 u; } v; v.f = f;
    u32 u = v.u;
    return (u16)((u + 0x7FFFu + ((u >> 16) & 1u)) >> 16);
}
__device__ __forceinline__ float silu_f(float a) {
    return a / (1.f + __expf(-a));
}
__device__ __forceinline__ float softplus_f(float z) {
    return (z > 15.f) ? z : __logf(1.f + __expf(z));
}

// ---------------- K0: fold merge+out weights ----------------
__global__ void k_prep(const float* __restrict__ ow, const float* __restrict__ mw,
                       const float* __restrict__ mg, const float* __restrict__ mb,
                       const float* __restrict__ ob,
                       float* __restrict__ Wt, float* __restrict__ rsum,
                       float* __restrict__ c0)
{
    __shared__ float mdot[DIN];
    int t = threadIdx.x; // 128 threads
    if (t < DIN) {
        float s = 0.f;
        for (int k = 0; k < 128; ++k) s += mw[t*128 + k] * mb[k];
        mdot[t] = s;
    }
    {
        int k = t;
        for (int o = 0; o < CIN; ++o) {
            float s = 0.f;
            for (int d = 0; d < DIN; ++d) s += ow[o*DIN + d] * mw[d*128 + k];
            Wt[k*CIN + o] = s * mg[k];
        }
    }
    __syncthreads();
    if (t < CIN) {
        float rs = 0.f;
        for (int k = 0; k < 128; ++k) rs += Wt[k*CIN + t];
        rsum[t] = rs;
        float c = ob[t];
        for (int d = 0; d < DIN; ++d) c += ow[t*DIN + d] * mdot[d];
        c0[t] = c;
    }
}

// ---------------- K1: layernorm(C=20) + inproj(20->32) + silu ----------------
__global__ __launch_bounds__(256) void k_lnproj(
    const float* __restrict__ x, const float* __restrict__ ng,
    const float* __restrict__ nb, const float* __restrict__ ipw,
    u16* __restrict__ h1)
{
    __shared__ float w_s[DIN*CIN];
    __shared__ float g_s[CIN], b_s[CIN];
    for (int i = threadIdx.x; i < DIN*CIN; i += 256) w_s[i] = ipw[i];
    if (threadIdx.x < CIN) { g_s[threadIdx.x] = ng[threadIdx.x]; b_s[threadIdx.x] = nb[threadIdx.x]; }
    __syncthreads();

    int p = blockIdx.x*256 + threadIdx.x;
    int b = p / HW, rem = p % HW;
    float v[CIN];
    float m = 0.f;
    #pragma unroll
    for (int c = 0; c < CIN; ++c) { v[c] = x[(b*CIN + c)*HW + rem]; m += v[c]; }
    m *= (1.f/CIN);
    float var = 0.f;
    #pragma unroll
    for (int c = 0; c < CIN; ++c) { float d = v[c]-m; var += d*d; }
    var *= (1.f/CIN);
    float rstd = rsqrtf(var + EPSF);
    #pragma unroll
    for (int c = 0; c < CIN; ++c) v[c] = (v[c]-m)*rstd*g_s[c] + b_s[c];

    float o[DIN];
    #pragma unroll
    for (int j = 0; j < DIN; ++j) {
        float acc = 0.f;
        #pragma unroll
        for (int c = 0; c < CIN; ++c) acc += w_s[j*CIN + c]*v[c];
        o[j] = silu_f(acc);
    }
    u32 pk[16];
    #pragma unroll
    for (int j2 = 0; j2 < 16; ++j2)
        pk[j2] = (u32)f2bf(o[2*j2]) | ((u32)f2bf(o[2*j2+1]) << 16);
    uint4* dst = (uint4*)(h1 + (size_t)p*DIN);
    dst[0] = make_uint4(pk[0],pk[1],pk[2],pk[3]);
    dst[1] = make_uint4(pk[4],pk[5],pk[6],pk[7]);
    dst[2] = make_uint4(pk[8],pk[9],pk[10],pk[11]);
    dst[3] = make_uint4(pk[12],pk[13],pk[14],pk[15]);
}

// ---------------- K2: depthwise 3x3 conv + bias + silu ----------------
__global__ __launch_bounds__(256) void k_conv(
    const u16* __restrict__ h1, const float* __restrict__ cw,
    const float* __restrict__ cb, u16* __restrict__ h2)
{
    __shared__ float w_s[9*DIN];
    __shared__ float b_s[DIN];
    for (int i = threadIdx.x; i < 9*DIN; i += 256) w_s[i] = cw[i];
    if (threadIdx.x < DIN) b_s[threadIdx.x] = cb[threadIdx.x];
    __syncthreads();

    int tid = blockIdx.x*256 + threadIdx.x;
    int p = tid >> 2, g = tid & 3;
    int b = p / HW, rem = p % HW;
    int yy0 = rem / WW, xx0 = rem % WW;

    float acc[8];
    #pragma unroll
    for (int i = 0; i < 8; ++i) acc[i] = b_s[g*8 + i];

    #pragma unroll
    for (int dy = -1; dy <= 1; ++dy) {
        int yy = yy0 + dy;
        #pragma unroll
        for (int dx = -1; dx <= 1; ++dx) {
            int xc = xx0 + dx;
            if (yy >= 0 && yy < HH && xc >= 0 && xc < WW) {
                uint4 q = *(const uint4*)(h1 + ((size_t)(b*HW + yy*WW + xc)*DIN + g*8));
                int k = (dy+1)*3 + (dx+1);
                const float* wp = &w_s[k*DIN + g*8];
                acc[0] += wp[0]*bflo(q.x);  acc[1] += wp[1]*bfhi(q.x);
                acc[2] += wp[2]*bflo(q.y);  acc[3] += wp[3]*bfhi(q.y);
                acc[4] += wp[4]*bflo(q.z);  acc[5] += wp[5]*bfhi(q.z);
                acc[6] += wp[6]*bflo(q.w);  acc[7] += wp[7]*bfhi(q.w);
            }
        }
    }
    u32 pk[4];
    #pragma unroll
    for (int i2 = 0; i2 < 4; ++i2) {
        float a = silu_f(acc[2*i2]);
        float c = silu_f(acc[2*i2+1]);
        pk[i2] = (u32)f2bf(a) | ((u32)f2bf(c) << 16);
    }
    *(uint4*)(h2 + ((size_t)p*DIN + g*8)) = make_uint4(pk[0],pk[1],pk[2],pk[3]);
}

// ---------------- K3a (small path): xdbl records (dl,B,C) = 40B ----------------
__global__ __launch_bounds__(256) void k_proj_small(
    const u16* __restrict__ h2, const float* __restrict__ xw,
    u16* __restrict__ proj)
{
    __shared__ float xw_s[4*CIN*DIN];
    for (int i = threadIdx.x; i < 4*CIN*DIN; i += 256) xw_s[i] = xw[i];
    __syncthreads();

    int p = blockIdx.x*256 + threadIdx.x;
    float u[DIN];
    const uint4* src = (const uint4*)(h2 + (size_t)p*DIN);
    #pragma unroll
    for (int q4 = 0; q4 < 4; ++q4) {
        uint4 v = src[q4];
        u[q4*8+0]=bflo(v.x); u[q4*8+1]=bfhi(v.x);
        u[q4*8+2]=bflo(v.y); u[q4*8+3]=bfhi(v.y);
        u[q4*8+4]=bflo(v.z); u[q4*8+5]=bfhi(v.z);
        u[q4*8+6]=bflo(v.w); u[q4*8+7]=bfhi(v.w);
    }
    #pragma unroll 1
    for (int dir = 0; dir < 4; ++dir) {
        float xd[CIN];
        #pragma unroll
        for (int j = 0; j < CIN; ++j) xd[j] = 0.f;
        #pragma unroll
        for (int d4 = 0; d4 < 8; ++d4) {
            float u0 = u[d4*4], u1 = u[d4*4+1], u2 = u[d4*4+2], u3 = u[d4*4+3];
            #pragma unroll
            for (int j = 0; j < CIN; ++j) {
                float4 w4 = *(const float4*)&xw_s[(dir*CIN + j)*DIN + d4*4];
                xd[j] += w4.x*u0 + w4.y*u1 + w4.z*u2 + w4.w*u3;
            }
        }
        u32 pk[10];
        #pragma unroll
        for (int i = 0; i < 10; ++i)
            pk[i] = (u32)f2bf(xd[2*i]) | ((u32)f2bf(xd[2*i+1]) << 16);
        uint2* dst = (uint2*)(proj + ((size_t)dir*BHW + p)*CIN);
        dst[0] = make_uint2(pk[0],pk[1]);
        dst[1] = make_uint2(pk[2],pk[3]);
        dst[2] = make_uint2(pk[4],pk[5]);
        dst[3] = make_uint2(pk[6],pk[7]);
        dst[4] = make_uint2(pk[8],pk[9]);
    }
}

// ---------------- K3b (big path): dt precompute + (B,C) records ----------------
// dtb: (dir,BHW,32) bf16 (64B/pixel/dir, coalesced); bcb: (dir,BHW,16) bf16 (32B).
__global__ __launch_bounds__(256) void k_proj_big(
    const u16* __restrict__ h2, const float* __restrict__ xw,
    const float* __restrict__ dwm, const float* __restrict__ dbv,
    u16* __restrict__ dtb, u16* __restrict__ bcb)
{
    __shared__ float xw_s[4*CIN*DIN];
    __shared__ float dw_s[4*DIN*4];
    __shared__ float db_s[4*DIN];
    for (int i = threadIdx.x; i < 4*CIN*DIN; i += 256) xw_s[i] = xw[i];
    for (int i = threadIdx.x; i < 4*DIN*4; i += 256)   dw_s[i] = dwm[i];
    if (threadIdx.x < 4*DIN) db_s[threadIdx.x] = dbv[threadIdx.x];
    __syncthreads();

    int p = blockIdx.x*256 + threadIdx.x;
    float u[DIN];
    const uint4* src = (const uint4*)(h2 + (size_t)p*DIN);
    #pragma unroll
    for (int q4 = 0; q4 < 4; ++q4) {
        uint4 v = src[q4];
        u[q4*8+0]=bflo(v.x); u[q4*8+1]=bfhi(v.x);
        u[q4*8+2]=bflo(v.y); u[q4*8+3]=bfhi(v.y);
        u[q4*8+4]=bflo(v.z); u[q4*8+5]=bfhi(v.z);
        u[q4*8+6]=bflo(v.w); u[q4*8+7]=bfhi(v.w);
    }
    #pragma unroll 1
    for (int dir = 0; dir < 4; ++dir) {
        float xd[CIN];
        #pragma unroll
        for (int j = 0; j < CIN; ++j) xd[j] = 0.f;
        #pragma unroll
        for (int d4 = 0; d4 < 8; ++d4) {
            float u0 = u[d4*4], u1 = u[d4*4+1], u2 = u[d4*4+2], u3 = u[d4*4+3];
            #pragma unroll
            for (int j = 0; j < CIN; ++j) {
                float4 w4 = *(const float4*)&xw_s[(dir*CIN + j)*DIN + d4*4];
                xd[j] += w4.x*u0 + w4.y*u1 + w4.z*u2 + w4.w*u3;
            }
        }
        // B,C record (16 bf16, 32B)
        {
            u32 pk[8];
            #pragma unroll
            for (int i = 0; i < 8; ++i)
                pk[i] = (u32)f2bf(xd[4+2*i]) | ((u32)f2bf(xd[5+2*i]) << 16);
            uint4* dst = (uint4*)(bcb + ((size_t)dir*BHW + p)*16);
            dst[0] = make_uint4(pk[0],pk[1],pk[2],pk[3]);
            dst[1] = make_uint4(pk[4],pk[5],pk[6],pk[7]);
        }
        // dt for 32 channels (32 bf16, 64B)
        {
            float d0 = xd[0], d1 = xd[1], d2 = xd[2], d3 = xd[3];
            u32 pk[16];
            #pragma unroll
            for (int dd = 0; dd < 16; ++dd) {
                const float4* w = (const float4*)&dw_s[(dir*DIN + dd*2)*4];
                float4 wa = w[0], wb = w[1];
                float za = db_s[dir*DIN + dd*2]   + wa.x*d0 + wa.y*d1 + wa.z*d2 + wa.w*d3;
                float zb = db_s[dir*DIN + dd*2+1] + wb.x*d0 + wb.y*d1 + wb.z*d2 + wb.w*d3;
                pk[dd] = (u32)f2bf(softplus_f(za)) | ((u32)f2bf(softplus_f(zb)) << 16);
            }
            uint4* dst = (uint4*)(dtb + ((size_t)dir*BHW + p)*DIN);
            dst[0] = make_uint4(pk[0], pk[1], pk[2], pk[3]);
            dst[1] = make_uint4(pk[4], pk[5], pk[6], pk[7]);
            dst[2] = make_uint4(pk[8], pk[9], pk[10],pk[11]);
            dst[3] = make_uint4(pk[12],pk[13],pk[14],pk[15]);
        }
    }
}

// ---------------- K4: 4-direction selective scan ----------------
// lane = d (32 ch), 2 sequences per wave, 8 states/lane as 4x float2.
// All base pointers have live GUARD bytes before/after the data region so
// depth-2 prefetch can overrun +-2 steps (up to +-49152 B) without faulting.
template<bool BIG>
__global__ __launch_bounds__(256) void k_scan(
    const char* __restrict__ h2b,   // u data at +GUARD
    const char* __restrict__ pb,    // BIG: dt data at +GUARD; small: 40B records at +GUARD
    const char* __restrict__ bcb,   // BIG: 32B (B,C) records at +GUARD
    const float* __restrict__ Alog, const float* __restrict__ Dp,
    const float* __restrict__ dwm,  const float* __restrict__ dbv,
    char* __restrict__ y4b)
{
    int tid  = blockIdx.x*256 + threadIdx.x;
    int wv   = tid >> 6, lane = tid & 63;
    int half = lane >> 5, d = lane & 31;
    int dir  = wv / 768;                 // uniform per wave (768 % 4 == 0)
    int s    = (wv % 768)*2 + half;
    int b    = s / 384, r = s % 384;

    int p0, stp;
    if (dir == 0)      { p0 = b*HW + r*WW;           stp = 1;  }
    else if (dir == 1) { p0 = b*HW + r*WW + (WW-1);  stp = -1; }
    else if (dir == 2) { p0 = b*HW + r;              stp = WW; }
    else               { p0 = b*HW + (HH-1)*WW + r;  stp = -WW;}

    f2 A2[4];
    #pragma unroll
    for (int j = 0; j < 4; ++j) {
        A2[j].x = -__expf(Alog[(dir*DIN + d)*8 + 2*j]);
        A2[j].y = -__expf(Alog[(dir*DIN + d)*8 + 2*j + 1]);
    }
    float Dd = Dp[dir*DIN + d];
    float dw0=0.f, dw1=0.f, dw2=0.f, dw3=0.f, dbc=0.f;
    if (!BIG) {
        dw0 = dwm[(dir*DIN + d)*4 + 0]; dw1 = dwm[(dir*DIN + d)*4 + 1];
        dw2 = dwm[(dir*DIN + d)*4 + 2]; dw3 = dwm[(dir*DIN + d)*4 + 3];
        dbc = dbv[dir*DIN + d];
    }

    // running byte offsets (u32; GUARD keeps them positive under overrun)
    u32 uo = GUARD + (u32)((p0*DIN + d)*2);                int su = stp*DIN*2;
    u32 yo = (u32)((p0*128 + dir*DIN + d)*2);              int sy = stp*256;
    u32 to = 0; int st = 0; u32 co = 0; int sc = 0;
    if (BIG) {
        to = GUARD + (u32)(((dir*BHW + p0)*DIN + d)*2);    st = su;
        co = GUARD + (u32)((dir*BHW + p0)*32);             sc = stp*32;
    } else {
        co = GUARD + (u32)((dir*BHW + p0)*CIN*2);          sc = stp*CIN*2;
    }

    u16 ub[2]; u16 tb[2];
    uint2 dlb[2], Bl[2], Bh[2], Cl[2], Ch[2];
    uint4 B4[2], C4[2];
    u32 fu = uo, ft = to, fc = co;

    auto fetch = [&](int sl) {
        ub[sl] = *(const u16*)(h2b + fu);
        if (BIG) {
            tb[sl] = *(const u16*)(pb + ft);
            B4[sl] = *(const uint4*)(bcb + fc);
            C4[sl] = *(const uint4*)(bcb + fc + 16);
            ft += (u32)st;
        } else {
            dlb[sl] = *(const uint2*)(pb + fc);
            Bl[sl]  = *(const uint2*)(pb + fc + 8);
            Bh[sl]  = *(const uint2*)(pb + fc + 16);
            Cl[sl]  = *(const uint2*)(pb + fc + 24);
            Ch[sl]  = *(const uint2*)(pb + fc + 32);
        }
        fu += (u32)su; fc += (u32)sc;
    };

    fetch(0); fetch(1);

    f2 h0 = {0.f,0.f}, h1 = {0.f,0.f}, h2v = {0.f,0.f}, h3 = {0.f,0.f};

    #pragma unroll 2
    for (int t = 0; t < 384; ++t) {
        int sl = t & 1;
        float uu = bf2f(ub[sl]);
        float dt;
        u32 bw0, bw1, bw2, bw3, cw0, cw1, cw2, cw3;
        if (BIG) {
            dt = bf2f(tb[sl]);
            uint4 Bv = B4[sl], Cv = C4[sl];
            bw0 = Bv.x; bw1 = Bv.y; bw2 = Bv.z; bw3 = Bv.w;
            cw0 = Cv.x; cw1 = Cv.y; cw2 = Cv.z; cw3 = Cv.w;
        } else {
            uint2 dl = dlb[sl];
            float z = dbc + dw0*bflo(dl.x) + dw1*bfhi(dl.x)
                          + dw2*bflo(dl.y) + dw3*bfhi(dl.y);
            dt = softplus_f(z);
            bw0 = Bl[sl].x; bw1 = Bl[sl].y; bw2 = Bh[sl].x; bw3 = Bh[sl].y;
            cw0 = Cl[sl].x; cw1 = Cl[sl].y; cw2 = Ch[sl].x; cw3 = Ch[sl].y;
        }
        fetch(sl);   // loads for t+2

        float dtu = dt * uu;
        f2 du2 = {dtu, dtu};
        f2 dt2 = {dt, dt};

        f2 e0 = dt2*A2[0], e1 = dt2*A2[1], e2 = dt2*A2[2], e3 = dt2*A2[3];
        f2 a0 = { __expf(e0.x), __expf(e0.y) };
        f2 a1 = { __expf(e1.x), __expf(e1.y) };
        f2 a2 = { __expf(e2.x), __expf(e2.y) };
        f2 a3 = { __expf(e3.x), __expf(e3.y) };

        f2 Bp0 = { bflo(bw0), bfhi(bw0) }, Bp1 = { bflo(bw1), bfhi(bw1) };
        f2 Bp2 = { bflo(bw2), bfhi(bw2) }, Bp3 = { bflo(bw3), bfhi(bw3) };
        f2 Cp0 = { bflo(cw0), bfhi(cw0) }, Cp1 = { bflo(cw1), bfhi(cw1) };
        f2 Cp2 = { bflo(cw2), bfhi(cw2) }, Cp3 = { bflo(cw3), bfhi(cw3) };

        h0  = __builtin_elementwise_fma(a0, h0,  du2*Bp0);
        h1  = __builtin_elementwise_fma(a1, h1,  du2*Bp1);
        h2v = __builtin_elementwise_fma(a2, h2v, du2*Bp2);
        h3  = __builtin_elementwise_fma(a3, h3,  du2*Bp3);

        f2 yv = Cp0*h0;
        yv = __builtin_elementwise_fma(Cp1, h1,  yv);
        yv = __builtin_elementwise_fma(Cp2, h2v, yv);
        yv = __builtin_elementwise_fma(Cp3, h3,  yv);

        float y = yv.x + yv.y + Dd*uu;
        *(u16*)(y4b + yo) = f2bf(y);
        yo += (u32)sy;
    }
}

// ---------------- K5: LN(128) + folded 128->20 + NCHW transpose ----------------
__global__ __launch_bounds__(256) void k_merge(
    const u16* __restrict__ y4, const float* __restrict__ Wt,
    const float* __restrict__ rsum, const float* __restrict__ c0,
    float* __restrict__ out)
{
    __shared__ float Wt_s[128*CIN];
    __shared__ float rs_s[CIN], c0_s[CIN];
    for (int i = threadIdx.x; i < 128*CIN; i += 256) Wt_s[i] = Wt[i];
    if (threadIdx.x < CIN) { rs_s[threadIdx.x] = rsum[threadIdx.x]; c0_s[threadIdx.x] = c0[threadIdx.x]; }
    __syncthreads();

    int p = blockIdx.x*256 + threadIdx.x;
    int b = p / HW, rem = p % HW;
    const uint4* src = (const uint4*)(y4 + (size_t)p*128);

    float s1 = 0.f, s2 = 0.f;
    #pragma unroll 4
    for (int q4 = 0; q4 < 16; ++q4) {
        uint4 v = src[q4];
        u32 w[4] = {v.x, v.y, v.z, v.w};
        #pragma unroll
        for (int i = 0; i < 4; ++i) {
            float a = bflo(w[i]); float c = bfhi(w[i]);
            s1 += a + c; s2 += a*a + c*c;
        }
    }
    float m = s1*(1.f/128.f);
    float var = s2*(1.f/128.f) - m*m;
    float rstd = rsqrtf(var + EPSF);

    float acc[CIN];
    #pragma unroll
    for (int o = 0; o < CIN; ++o) acc[o] = 0.f;

    #pragma unroll 2
    for (int q4 = 0; q4 < 16; ++q4) {
        uint4 v = src[q4];
        u32 w[4] = {v.x, v.y, v.z, v.w};
        #pragma unroll
        for (int i = 0; i < 4; ++i) {
            int k = q4*8 + i*2;
            float a = bflo(w[i]); float c = bfhi(w[i]);
            const float4* w0 = (const float4*)&Wt_s[k*CIN];
            const float4* w1 = (const float4*)&Wt_s[(k+1)*CIN];
            #pragma unroll
            for (int o4 = 0; o4 < 5; ++o4) {
                float4 x0 = w0[o4], x1 = w1[o4];
                acc[o4*4+0] += x0.x*a + x1.x*c;
                acc[o4*4+1] += x0.y*a + x1.y*c;
                acc[o4*4+2] += x0.z*a + x1.z*c;
                acc[o4*4+3] += x0.w*a + x1.w*c;
            }
        }
    }
    #pragma unroll
    for (int o = 0; o < CIN; ++o) {
        float res = rstd*(acc[o] - m*rs_s[o]) + c0_s[o];
        out[(b*CIN + o)*HW + rem] = res;
    }
}

extern "C" void kernel_launch(void* const* d_in, const int* in_sizes, int n_in,
                              void* d_out, int out_size, void* d_ws, size_t ws_size,
                              hipStream_t stream)
{
    const float* x    = (const float*)d_in[0];
    const float* ng   = (const float*)d_in[1];
    const float* nb   = (const float*)d_in[2];
    const float* ipw  = (const float*)d_in[3];
    const float* cw   = (const float*)d_in[4];
    const float* cb   = (const float*)d_in[5];
    const float* xw   = (const float*)d_in[6];
    const float* dwm  = (const float*)d_in[7];
    const float* dbv  = (const float*)d_in[8];
    const float* Alog = (const float*)d_in[9];
    const float* Dpv  = (const float*)d_in[10];
    const float* mg   = (const float*)d_in[11];
    const float* mb   = (const float*)d_in[12];
    const float* mw   = (const float*)d_in[13];
    const float* ow   = (const float*)d_in[14];
    const float* ob   = (const float*)d_in[15];
    float* out = (float*)d_out;

    const size_t y4_bytes = (size_t)BHW*128*2;       // 150,994,944
    const size_t dt_bytes = (size_t)4*BHW*DIN*2;     // 150,994,944
    const size_t bc_bytes = (size_t)4*BHW*16*2;      //  75,497,472
    const size_t pr_bytes = (size_t)4*BHW*CIN*2;     //  94,371,840
    const size_t wt_bytes = (size_t)(128*CIN + 64)*4;

    char* ws = (char*)d_ws;
    u16* y4 = (u16*)ws;
    u16* h1 = y4;                                    // alias: h1 dead before y4 written

    size_t dt_pos = y4_bytes + GUARD;                // also pr_pos for small path
    size_t bc_pos = dt_pos + dt_bytes + GUARD;
    size_t need_big   = bc_pos + bc_bytes + GUARD + wt_bytes + GUARD;
    size_t need_small = dt_pos + pr_bytes + GUARD + wt_bytes + GUARD;

    if (ws_size < need_small) {
        hipMemsetAsync(d_out, 0x7F, (size_t)out_size*4, stream);  // diagnosable sentinel
        return;
    }
    bool big = (ws_size >= need_big);

    // h2 (u after conv) lives inside d_out with GUARD on both sides.
    char* h2base = (char*)d_out;                     // data at +GUARD
    u16*  h2 = (u16*)(h2base + GUARD);               // 37.75 MB + guards < 47.19 MB

    float *Wt, *rsum, *c0;
    if (big) {
        Wt = (float*)(ws + bc_pos + bc_bytes + GUARD);
    } else {
        Wt = (float*)(ws + dt_pos + pr_bytes + GUARD);
    }
    rsum = Wt + 128*CIN; c0 = rsum + 32;

    k_prep  <<<1, 128, 0, stream>>>(ow, mw, mg, mb, ob, Wt, rsum, c0);
    k_lnproj<<<BHW/256, 256, 0, stream>>>(x, ng, nb, ipw, h1);
    k_conv  <<<BHW*4/256, 256, 0, stream>>>(h1, cw, cb, h2);

    if (big) {
        u16* dtb = (u16*)(ws + dt_pos);
        u16* bcb = (u16*)(ws + bc_pos);
        k_proj_big<<<BHW/256, 256, 0, stream>>>(h2, xw, dwm, dbv, dtb, bcb);
        k_scan<true><<<768, 256, 0, stream>>>(
            h2base, (const char*)(ws + dt_pos - GUARD), (const char*)(ws + bc_pos - GUARD),
            Alog, Dpv, dwm, dbv, (char*)y4);
    } else {
        u16* proj = (u16*)(ws + dt_pos);
        k_proj_small<<<BHW/256, 256, 0, stream>>>(h2, xw, proj);
        k_scan<false><<<768, 256, 0, stream>>>(
            h2base, (const char*)(ws + dt_pos - GUARD), (const char*)nullptr,
            Alog, Dpv, dwm, dbv, (char*)y4);
    }

    k_merge <<<BHW/256, 256, 0, stream>>>(y4, Wt, rsum, c0, out);
}

// Round 3
// 530.320 us; speedup vs baseline: 1.4111x; 1.2420x over previous
//
#include <hip/hip_runtime.h>

typedef unsigned short u16;
typedef unsigned int   u32;
typedef unsigned long long u64;
typedef float f2 __attribute__((ext_vector_type(2)));

#define CIN  20
#define DIN  32
#define BB   4
#define HH   384
#define WW   384
#define HW   147456
#define BHW  589824
#define EPSF 1e-5f
#define GUARD 65536

__device__ __forceinline__ float bflo(u32 u) {
    union { u32 v; float f; } x; x.v = u << 16; return x.f;
}
__device__ __forceinline__ float bfhi(u32 u) {
    union { u32 v; float f; } x; x.v = u & 0xffff0000u; return x.f;
}
__device__ __forceinline__ float bf2f(u16 h) {
    union { u32 v; float f; } x; x.v = ((u32)h) << 16; return x.f;
}
__device__ __forceinline__ u16 f2bf(float f) {
    union { float f; u32 u; } v; v.f = f;
    u32 u = v.u;
    return (u16)((u + 0x7FFFu + ((u >> 16) & 1u)) >> 16);
}
__device__ __forceinline__ float silu_f(float a) {
    return a / (1.f + __expf(-a));
}
__device__ __forceinline__ float softplus_f(float z) {
    return (z > 15.f) ? z : __logf(1.f + __expf(z));
}

// ---------------- K0: fold merge+out weights ----------------
__global__ void k_prep(const float* __restrict__ ow, const float* __restrict__ mw,
                       const float* __restrict__ mg, const float* __restrict__ mb,
                       const float* __restrict__ ob,
                       float* __restrict__ Wt, float* __restrict__ rsum,
                       float* __restrict__ c0)
{
    __shared__ float mdot[DIN];
    int t = threadIdx.x; // 128 threads
    if (t < DIN) {
        float s = 0.f;
        for (int k = 0; k < 128; ++k) s += mw[t*128 + k] * mb[k];
        mdot[t] = s;
    }
    {
        int k = t;
        for (int o = 0; o < CIN; ++o) {
            float s = 0.f;
            for (int d = 0; d < DIN; ++d) s += ow[o*DIN + d] * mw[d*128 + k];
            Wt[k*CIN + o] = s * mg[k];
        }
    }
    __syncthreads();
    if (t < CIN) {
        float rs = 0.f;
        for (int k = 0; k < 128; ++k) rs += Wt[k*CIN + t];
        rsum[t] = rs;
        float c = ob[t];
        for (int d = 0; d < DIN; ++d) c += ow[t*DIN + d] * mdot[d];
        c0[t] = c;
    }
}

// ---------------- K1: layernorm(C=20) + inproj(20->32) + silu ----------------
__global__ __launch_bounds__(256) void k_lnproj(
    const float* __restrict__ x, const float* __restrict__ ng,
    const float* __restrict__ nb, const float* __restrict__ ipw,
    u16* __restrict__ h1)
{
    __shared__ float w_s[DIN*CIN];
    __shared__ float g_s[CIN], b_s[CIN];
    for (int i = threadIdx.x; i < DIN*CIN; i += 256) w_s[i] = ipw[i];
    if (threadIdx.x < CIN) { g_s[threadIdx.x] = ng[threadIdx.x]; b_s[threadIdx.x] = nb[threadIdx.x]; }
    __syncthreads();

    int p = blockIdx.x*256 + threadIdx.x;
    int b = p / HW, rem = p % HW;
    float v[CIN];
    float m = 0.f;
    #pragma unroll
    for (int c = 0; c < CIN; ++c) { v[c] = x[(b*CIN + c)*HW + rem]; m += v[c]; }
    m *= (1.f/CIN);
    float var = 0.f;
    #pragma unroll
    for (int c = 0; c < CIN; ++c) { float d = v[c]-m; var += d*d; }
    var *= (1.f/CIN);
    float rstd = rsqrtf(var + EPSF);
    #pragma unroll
    for (int c = 0; c < CIN; ++c) v[c] = (v[c]-m)*rstd*g_s[c] + b_s[c];

    float o[DIN];
    #pragma unroll
    for (int j = 0; j < DIN; ++j) {
        float acc = 0.f;
        #pragma unroll
        for (int c = 0; c < CIN; ++c) acc += w_s[j*CIN + c]*v[c];
        o[j] = silu_f(acc);
    }
    u32 pk[16];
    #pragma unroll
    for (int j2 = 0; j2 < 16; ++j2)
        pk[j2] = (u32)f2bf(o[2*j2]) | ((u32)f2bf(o[2*j2+1]) << 16);
    uint4* dst = (uint4*)(h1 + (size_t)p*DIN);
    dst[0] = make_uint4(pk[0],pk[1],pk[2],pk[3]);
    dst[1] = make_uint4(pk[4],pk[5],pk[6],pk[7]);
    dst[2] = make_uint4(pk[8],pk[9],pk[10],pk[11]);
    dst[3] = make_uint4(pk[12],pk[13],pk[14],pk[15]);
}

// ---------------- K2: depthwise 3x3 conv + bias + silu ----------------
__global__ __launch_bounds__(256) void k_conv(
    const u16* __restrict__ h1, const float* __restrict__ cw,
    const float* __restrict__ cb, u16* __restrict__ h2)
{
    __shared__ float w_s[9*DIN];
    __shared__ float b_s[DIN];
    for (int i = threadIdx.x; i < 9*DIN; i += 256) w_s[i] = cw[i];
    if (threadIdx.x < DIN) b_s[threadIdx.x] = cb[threadIdx.x];
    __syncthreads();

    int tid = blockIdx.x*256 + threadIdx.x;
    int p = tid >> 2, g = tid & 3;
    int b = p / HW, rem = p % HW;
    int yy0 = rem / WW, xx0 = rem % WW;

    float acc[8];
    #pragma unroll
    for (int i = 0; i < 8; ++i) acc[i] = b_s[g*8 + i];

    #pragma unroll
    for (int dy = -1; dy <= 1; ++dy) {
        int yy = yy0 + dy;
        #pragma unroll
        for (int dx = -1; dx <= 1; ++dx) {
            int xc = xx0 + dx;
            if (yy >= 0 && yy < HH && xc >= 0 && xc < WW) {
                uint4 q = *(const uint4*)(h1 + ((size_t)(b*HW + yy*WW + xc)*DIN + g*8));
                int k = (dy+1)*3 + (dx+1);
                const float* wp = &w_s[k*DIN + g*8];
                acc[0] += wp[0]*bflo(q.x);  acc[1] += wp[1]*bfhi(q.x);
                acc[2] += wp[2]*bflo(q.y);  acc[3] += wp[3]*bfhi(q.y);
                acc[4] += wp[4]*bflo(q.z);  acc[5] += wp[5]*bfhi(q.z);
                acc[6] += wp[6]*bflo(q.w);  acc[7] += wp[7]*bfhi(q.w);
            }
        }
    }
    u32 pk[4];
    #pragma unroll
    for (int i2 = 0; i2 < 4; ++i2) {
        float a = silu_f(acc[2*i2]);
        float c = silu_f(acc[2*i2+1]);
        pk[i2] = (u32)f2bf(a) | ((u32)f2bf(c) << 16);
    }
    *(uint4*)(h2 + ((size_t)p*DIN + g*8)) = make_uint4(pk[0],pk[1],pk[2],pk[3]);
}

// ---------------- K3: xdbl -> dl array (8B/rec) + BC array (32B/rec) ----------------
__global__ __launch_bounds__(256) void k_proj(
    const u16* __restrict__ h2, const float* __restrict__ xw,
    u16* __restrict__ dlA, u16* __restrict__ bcA)
{
    __shared__ float xw_s[4*CIN*DIN];
    for (int i = threadIdx.x; i < 4*CIN*DIN; i += 256) xw_s[i] = xw[i];
    __syncthreads();

    int p = blockIdx.x*256 + threadIdx.x;
    float u[DIN];
    const uint4* src = (const uint4*)(h2 + (size_t)p*DIN);
    #pragma unroll
    for (int q4 = 0; q4 < 4; ++q4) {
        uint4 v = src[q4];
        u[q4*8+0]=bflo(v.x); u[q4*8+1]=bfhi(v.x);
        u[q4*8+2]=bflo(v.y); u[q4*8+3]=bfhi(v.y);
        u[q4*8+4]=bflo(v.z); u[q4*8+5]=bfhi(v.z);
        u[q4*8+6]=bflo(v.w); u[q4*8+7]=bfhi(v.w);
    }
    #pragma unroll 1
    for (int dir = 0; dir < 4; ++dir) {
        float xd[CIN];
        #pragma unroll
        for (int j = 0; j < CIN; ++j) xd[j] = 0.f;
        #pragma unroll
        for (int d4 = 0; d4 < 8; ++d4) {
            float u0 = u[d4*4], u1 = u[d4*4+1], u2 = u[d4*4+2], u3 = u[d4*4+3];
            #pragma unroll
            for (int j = 0; j < CIN; ++j) {
                float4 w4 = *(const float4*)&xw_s[(dir*CIN + j)*DIN + d4*4];
                xd[j] += w4.x*u0 + w4.y*u1 + w4.z*u2 + w4.w*u3;
            }
        }
        u32 pk[10];
        #pragma unroll
        for (int i = 0; i < 10; ++i)
            pk[i] = (u32)f2bf(xd[2*i]) | ((u32)f2bf(xd[2*i+1]) << 16);
        *(uint2*)(dlA + (size_t)(dir*BHW + p)*4) = make_uint2(pk[0], pk[1]);
        uint4* bcd = (uint4*)(bcA + (size_t)(dir*BHW + p)*16);
        bcd[0] = make_uint4(pk[2], pk[3], pk[4], pk[5]);   // B0..B7
        bcd[1] = make_uint4(pk[6], pk[7], pk[8], pk[9]);   // C0..C7
    }
}

// ---------------- K4: 4-direction selective scan ----------------
// lane = d (32 ch), 2 sequences per wave, 8 states/lane as 4x float2.
// Fast path (validated vs Alog on device): a_n = r^(n+1) with r = sigmoid(-z),
// dt = -log(r). One exp + one rcp + one log per step vs 9 exps generic.
__global__ __launch_bounds__(256) void k_scan(
    const char* __restrict__ h2b,   // u data at +GUARD
    const char* __restrict__ dlb_,  // dl data at +GUARD (8B records)
    const char* __restrict__ bcb_,  // (B,C) data at +GUARD (32B records)
    const float* __restrict__ Alog, const float* __restrict__ Dp,
    const float* __restrict__ dwm,  const float* __restrict__ dbv,
    char* __restrict__ y4b)         // planar (dir, pixel, 32) bf16
{
    int tid  = blockIdx.x*256 + threadIdx.x;
    int wv   = tid >> 6, lane = tid & 63;
    int half = lane >> 5, d = lane & 31;
    int dir  = wv / 768;                 // uniform per wave
    int s    = (wv % 768)*2 + half;
    int b    = s / 384, r = s % 384;

    int p0, stp;
    if (dir == 0)      { p0 = b*HW + r*WW;           stp = 1;  }
    else if (dir == 1) { p0 = b*HW + r*WW + (WW-1);  stp = -1; }
    else if (dir == 2) { p0 = b*HW + r;              stp = WW; }
    else               { p0 = b*HW + (HH-1)*WW + r;  stp = -WW;}

    // A values + fast-path pattern check (A_n == -(n+1) for this lane's row)
    float Av[8];
    bool okl = true;
    #pragma unroll
    for (int j = 0; j < 8; ++j) {
        float e = __expf(Alog[(dir*DIN + d)*8 + j]);
        Av[j] = -e;
        okl = okl && (__builtin_fabsf(e - (float)(j+1)) < 2e-3f);
    }
    bool fast = (__ballot(okl) == ~0ull);

    float Dd  = Dp[dir*DIN + d];
    float dw0 = dwm[(dir*DIN + d)*4 + 0], dw1 = dwm[(dir*DIN + d)*4 + 1];
    float dw2 = dwm[(dir*DIN + d)*4 + 2], dw3 = dwm[(dir*DIN + d)*4 + 3];
    float dbc = dbv[dir*DIN + d];

    // running byte offsets (u32; GUARD keeps them positive under +-2-step overrun)
    u32 uo = GUARD + (u32)((p0*DIN + d)*2);            int su = stp*DIN*2;
    u32 yo = (u32)((dir*BHW + p0)*64 + d*2);           int sy = stp*64;
    u32 c1 = GUARD + (u32)((dir*BHW + p0)*8);          int s1 = stp*8;
    u32 c2 = GUARD + (u32)((dir*BHW + p0)*32);         int s2 = stp*32;

    u16 ub[2]; uint2 dlr[2]; uint4 B4[2], C4[2];
    u32 fu = uo, f1 = c1, f2o = c2;

    auto fetch = [&](int sl) {
        ub[sl]  = *(const u16*)(h2b + fu);
        dlr[sl] = *(const uint2*)(dlb_ + f1);
        B4[sl]  = *(const uint4*)(bcb_ + f2o);
        C4[sl]  = *(const uint4*)(bcb_ + f2o + 16);
        fu += (u32)su; f1 += (u32)s1; f2o += (u32)s2;
    };

    fetch(0); fetch(1);

    f2 h0 = {0.f,0.f}, h1 = {0.f,0.f}, h2v = {0.f,0.f}, h3 = {0.f,0.f};

    if (fast) {
        #pragma unroll 2
        for (int t = 0; t < 384; ++t) {
            int sl = t & 1;
            float uu = bf2f(ub[sl]);
            uint2 dl = dlr[sl];
            uint4 Bv = B4[sl], Cv = C4[sl];
            fetch(sl);   // loads for t+2

            float z = dbc + dw0*bflo(dl.x) + dw1*bfhi(dl.x)
                          + dw2*bflo(dl.y) + dw3*bfhi(dl.y);
            z = fminf(z, 80.f);
            float rr = __builtin_amdgcn_rcpf(1.f + __expf(z)); // = exp(-dt)
            float dt = -__logf(rr);
            float r2 = rr*rr;
            f2 rr2 = {r2, r2};
            f2 a01 = {rr, r2};
            f2 a23 = a01*rr2;
            f2 a45 = a23*rr2;
            f2 a67 = a45*rr2;

            float dtu = dt*uu;
            f2 du2 = {dtu, dtu};
            f2 Bp0 = { bflo(Bv.x), bfhi(Bv.x) }, Bp1 = { bflo(Bv.y), bfhi(Bv.y) };
            f2 Bp2 = { bflo(Bv.z), bfhi(Bv.z) }, Bp3 = { bflo(Bv.w), bfhi(Bv.w) };
            f2 Cp0 = { bflo(Cv.x), bfhi(Cv.x) }, Cp1 = { bflo(Cv.y), bfhi(Cv.y) };
            f2 Cp2 = { bflo(Cv.z), bfhi(Cv.z) }, Cp3 = { bflo(Cv.w), bfhi(Cv.w) };

            h0  = __builtin_elementwise_fma(a01, h0,  du2*Bp0);
            h1  = __builtin_elementwise_fma(a23, h1,  du2*Bp1);
            h2v = __builtin_elementwise_fma(a45, h2v, du2*Bp2);
            h3  = __builtin_elementwise_fma(a67, h3,  du2*Bp3);

            f2 yv = Cp0*h0;
            yv = __builtin_elementwise_fma(Cp1, h1,  yv);
            yv = __builtin_elementwise_fma(Cp2, h2v, yv);
            yv = __builtin_elementwise_fma(Cp3, h3,  yv);

            float y = yv.x + yv.y + Dd*uu;
            *(u16*)(y4b + yo) = f2bf(y);
            yo += (u32)sy;
        }
    } else {
        f2 A2[4];
        #pragma unroll
        for (int j = 0; j < 4; ++j) { A2[j].x = Av[2*j]; A2[j].y = Av[2*j+1]; }
        #pragma unroll 2
        for (int t = 0; t < 384; ++t) {
            int sl = t & 1;
            float uu = bf2f(ub[sl]);
            uint2 dl = dlr[sl];
            uint4 Bv = B4[sl], Cv = C4[sl];
            fetch(sl);

            float z = dbc + dw0*bflo(dl.x) + dw1*bfhi(dl.x)
                          + dw2*bflo(dl.y) + dw3*bfhi(dl.y);
            float dt = softplus_f(z);
            f2 dt2 = {dt, dt};
            f2 e0 = dt2*A2[0], e1 = dt2*A2[1], e2 = dt2*A2[2], e3 = dt2*A2[3];
            f2 a01 = { __expf(e0.x), __expf(e0.y) };
            f2 a23 = { __expf(e1.x), __expf(e1.y) };
            f2 a45 = { __expf(e2.x), __expf(e2.y) };
            f2 a67 = { __expf(e3.x), __expf(e3.y) };

            float dtu = dt*uu;
            f2 du2 = {dtu, dtu};
            f2 Bp0 = { bflo(Bv.x), bfhi(Bv.x) }, Bp1 = { bflo(Bv.y), bfhi(Bv.y) };
            f2 Bp2 = { bflo(Bv.z), bfhi(Bv.z) }, Bp3 = { bflo(Bv.w), bfhi(Bv.w) };
            f2 Cp0 = { bflo(Cv.x), bfhi(Cv.x) }, Cp1 = { bflo(Cv.y), bfhi(Cv.y) };
            f2 Cp2 = { bflo(Cv.z), bfhi(Cv.z) }, Cp3 = { bflo(Cv.w), bfhi(Cv.w) };

            h0  = __builtin_elementwise_fma(a01, h0,  du2*Bp0);
            h1  = __builtin_elementwise_fma(a23, h1,  du2*Bp1);
            h2v = __builtin_elementwise_fma(a45, h2v, du2*Bp2);
            h3  = __builtin_elementwise_fma(a67, h3,  du2*Bp3);

            f2 yv = Cp0*h0;
            yv = __builtin_elementwise_fma(Cp1, h1,  yv);
            yv = __builtin_elementwise_fma(Cp2, h2v, yv);
            yv = __builtin_elementwise_fma(Cp3, h3,  yv);

            float y = yv.x + yv.y + Dd*uu;
            *(u16*)(y4b + yo) = f2bf(y);
            yo += (u32)sy;
        }
    }
}

// ---------------- K5: LN(128) + folded 128->20 + NCHW transpose ----------------
// Planar y4 (dir, pixel, 32): single pass, thread reads 4 x 64B contiguous.
__global__ __launch_bounds__(256) void k_merge(
    const u16* __restrict__ y4, const float* __restrict__ Wt,
    const float* __restrict__ rsum, const float* __restrict__ c0,
    float* __restrict__ out)
{
    __shared__ float Wt_s[128*CIN];
    __shared__ float rs_s[CIN], c0_s[CIN];
    for (int i = threadIdx.x; i < 128*CIN; i += 256) Wt_s[i] = Wt[i];
    if (threadIdx.x < CIN) { rs_s[threadIdx.x] = rsum[threadIdx.x]; c0_s[threadIdx.x] = c0[threadIdx.x]; }
    __syncthreads();

    int p = blockIdx.x*256 + threadIdx.x;
    int b = p / HW, rem = p % HW;

    float s1 = 0.f, s2 = 0.f;
    float acc[CIN];
    #pragma unroll
    for (int o = 0; o < CIN; ++o) acc[o] = 0.f;

    #pragma unroll 1
    for (int dirk = 0; dirk < 4; ++dirk) {
        const uint4* src = (const uint4*)(y4 + ((size_t)dirk*BHW + p)*32);
        #pragma unroll
        for (int q4 = 0; q4 < 4; ++q4) {
            uint4 v = src[q4];
            u32 w[4] = {v.x, v.y, v.z, v.w};
            #pragma unroll
            for (int i = 0; i < 4; ++i) {
                int k = dirk*32 + q4*8 + i*2;
                float a = bflo(w[i]); float c = bfhi(w[i]);
                s1 += a + c; s2 += a*a + c*c;
                const float4* w0 = (const float4*)&Wt_s[k*CIN];
                const float4* w1 = (const float4*)&Wt_s[(k+1)*CIN];
                #pragma unroll
                for (int o4 = 0; o4 < 5; ++o4) {
                    float4 x0 = w0[o4], x1 = w1[o4];
                    acc[o4*4+0] += x0.x*a + x1.x*c;
                    acc[o4*4+1] += x0.y*a + x1.y*c;
                    acc[o4*4+2] += x0.z*a + x1.z*c;
                    acc[o4*4+3] += x0.w*a + x1.w*c;
                }
            }
        }
    }
    float m = s1*(1.f/128.f);
    float var = s2*(1.f/128.f) - m*m;
    float rstd = rsqrtf(var + EPSF);
    #pragma unroll
    for (int o = 0; o < CIN; ++o) {
        float res = rstd*(acc[o] - m*rs_s[o]) + c0_s[o];
        out[(b*CIN + o)*HW + rem] = res;
    }
}

extern "C" void kernel_launch(void* const* d_in, const int* in_sizes, int n_in,
                              void* d_out, int out_size, void* d_ws, size_t ws_size,
                              hipStream_t stream)
{
    const float* x    = (const float*)d_in[0];
    const float* ng   = (const float*)d_in[1];
    const float* nb   = (const float*)d_in[2];
    const float* ipw  = (const float*)d_in[3];
    const float* cw   = (const float*)d_in[4];
    const float* cb   = (const float*)d_in[5];
    const float* xw   = (const float*)d_in[6];
    const float* dwm  = (const float*)d_in[7];
    const float* dbv  = (const float*)d_in[8];
    const float* Alog = (const float*)d_in[9];
    const float* Dpv  = (const float*)d_in[10];
    const float* mg   = (const float*)d_in[11];
    const float* mb   = (const float*)d_in[12];
    const float* mw   = (const float*)d_in[13];
    const float* ow   = (const float*)d_in[14];
    const float* ob   = (const float*)d_in[15];
    float* out = (float*)d_out;

    const size_t y4_bytes = (size_t)4*BHW*DIN*2;     // 150,994,944 (planar)
    const size_t dl_bytes = (size_t)4*BHW*8;         //  18,874,368
    const size_t bc_bytes = (size_t)4*BHW*32;        //  75,497,472
    const size_t wt_bytes = (size_t)(128*CIN + 64)*4;

    char* ws = (char*)d_ws;
    u16* y4 = (u16*)ws;
    u16* h1 = y4;                                    // alias: h1 dead before y4 written

    size_t dl_pos = y4_bytes + GUARD;
    size_t bc_pos = dl_pos + dl_bytes + GUARD;
    size_t wt_pos = bc_pos + bc_bytes + GUARD;
    size_t need   = wt_pos + wt_bytes + GUARD;       // ~245.6 MB (proven budget)

    if (ws_size < need) {
        hipMemsetAsync(d_out, 0x7F, (size_t)out_size*4, stream);  // diagnosable sentinel
        return;
    }

    // h2 (u after conv) lives inside d_out with GUARD on both sides.
    char* h2base = (char*)d_out;                     // data at +GUARD
    u16*  h2 = (u16*)(h2base + GUARD);               // 37.75 MB + guards < 47.19 MB

    u16* dlA = (u16*)(ws + dl_pos);
    u16* bcA = (u16*)(ws + bc_pos);
    float* Wt   = (float*)(ws + wt_pos);
    float* rsum = Wt + 128*CIN;
    float* c0   = rsum + 32;

    k_prep  <<<1, 128, 0, stream>>>(ow, mw, mg, mb, ob, Wt, rsum, c0);
    k_lnproj<<<BHW/256, 256, 0, stream>>>(x, ng, nb, ipw, h1);
    k_conv  <<<BHW*4/256, 256, 0, stream>>>(h1, cw, cb, h2);
    k_proj  <<<BHW/256, 256, 0, stream>>>(h2, xw, dlA, bcA);
    k_scan  <<<768, 256, 0, stream>>>(
        h2base, (const char*)(ws + dl_pos - GUARD), (const char*)(ws + bc_pos - GUARD),
        Alog, Dpv, dwm, dbv, (char*)y4);
    k_merge <<<BHW/256, 256, 0, stream>>>(y4, Wt, rsum, c0, out);
}